// Round 18
// baseline (43.320 us; speedup 1.0000x reference)
//
#include <hip/hip_runtime.h>
#include <hip/hip_bf16.h>

typedef short bfrag8 __attribute__((ext_vector_type(8)));
typedef float f32x4v __attribute__((ext_vector_type(4)));
typedef int i32x4 __attribute__((ext_vector_type(4)));
typedef unsigned short U16;
typedef unsigned int U32;

#define NN 4096
#define DD 128

static __device__ __forceinline__ U16 f2bf(float f){
  union { __hip_bfloat16 b; U16 u; } cv;
  cv.b = __float2bfloat16(f);
  return cv.u;
}

static __device__ __forceinline__ float bf2f(U32 u){
  union { float f; U32 u; } cv;
  cv.u = u << 16;
  return cv.f;
}

// i8 A-fragment (4 regs, 16 bytes of 0/1) from INVERTED adjacency bits.
static __device__ __forceinline__ i32x4 afragi8(U32 wl, U32 wh, int grp, U32 mul){
  U32 y = ((grp & 2) ? wh : wl) >> ((grp & 1) * 16);
  i32x4 a;
  a[0] = (int)((((y >>  0) & 0xFu) * mul) & 0x01010101u);
  a[1] = (int)((((y >>  4) & 0xFu) * mul) & 0x01010101u);
  a[2] = (int)((((y >>  8) & 0xFu) * mul) & 0x01010101u);
  a[3] = (int)((((y >> 12) & 0xFu) * mul) & 0x01010101u);
  return a;
}

// ---------------- kernel 0: W^T only ----------------
__global__ __launch_bounds__(256) void k0_wt(const float* __restrict__ W,
                                             U16* __restrict__ WT){
  int i = blockIdx.x*256 + threadIdx.x;      // i = d*128 + dp
  int d = i >> 7, dp = i & 127;
  WT[dp*128 + d] = f2bf(W[i]);
}

// ---------------- fused prep: bids<256 = k1 body; bids>=256 = lean adj pack ------
// Pack blocks carry the (unused) LDS allocation; 2 blocks/CU co-reside, so pack
// streaming overlaps compute-block latency. No shared barriers across roles.
__global__ __launch_bounds__(512) void kP(
    const float* __restrict__ x, const U16* __restrict__ WT,
    const int* __restrict__ adj,
    const float* __restrict__ nw, const float* __restrict__ nb,
    const float* __restrict__ gamma, const float* __restrict__ beta,
    U16* __restrict__ h_lnB, char* __restrict__ hTi8,
    U32* __restrict__ adjbT)
{
  __shared__ char smem[66560];               // 32K WT | 32K x-slab | 1K LN exchange
  const int tid = threadIdx.x;

  if (blockIdx.x >= 256){
    // ---------- lean pack: adjbT[g*4096+row] bit j = (adj[row][g*32+j]==0) ----
    int gid = (blockIdx.x - 256)*512 + tid;  // 0..524287 = 4096 rows x 128 g
    int g = gid >> 12, row = gid & 4095;
    const int4* src = reinterpret_cast<const int4*>(adj + (size_t)row*NN + g*32);
    int4 v[8];
    #pragma unroll
    for (int c = 0; c < 8; ++c) v[c] = src[c];
    U32 m = 0;
    #pragma unroll
    for (int c = 0; c < 8; ++c){
      m |= (v[c].x != 0 ? 0u : 1u) << (c*4);
      m |= (v[c].y != 0 ? 0u : 2u) << (c*4);
      m |= (v[c].z != 0 ? 0u : 4u) << (c*4);
      m |= (v[c].w != 0 ? 0u : 8u) << (c*4);
    }
    adjbT[(size_t)g*4096 + row] = m;
    return;
  }

  // ---------- k1 body (frozen R16): 8 waves = 4 row-groups x 2 col-halves ----
  U16* lds = reinterpret_cast<U16*>(smem);
  float4* xs4 = reinterpret_cast<float4*>(smem + 32768);
  float2* lnx = reinterpret_cast<float2*>(smem + 65536);   // [2 ch][64 rows]
  const int lane = tid & 63, w = tid >> 6;
  const int rh = w >> 1, ch = w & 1;
  const int l15 = lane & 15, grp = lane >> 4;

  #pragma unroll
  for (int q = 0; q < 4; ++q){
    int cid = q*512 + tid;
    int dp = cid >> 4, c = cid & 15;
    *reinterpret_cast<int4*>(lds + dp*128 + ((c*8) ^ ((dp&15)<<3))) =
        *reinterpret_cast<const int4*>(WT + cid*8);
  }
  {
    const float4* xg = reinterpret_cast<const float4*>(x) + (size_t)blockIdx.x*2048;
    #pragma unroll
    for (int k = 0; k < 4; ++k){
      int g = k*512 + tid;                   // 0..2047
      int row = g >> 5, c = g & 31;
      xs4[row*32 + ((c + row*2) & 31)] = xg[g];
    }
  }
  __syncthreads();

  const int rA = blockIdx.x*64 + rh*16 + l15;
  const int nA = rA & 4095;
  const float wgt = nw[nA] + 1.0f, bia = nb[nA];
  const int xrow = rh*16 + l15;

  f32x4v acc[4] = {};
  #pragma unroll
  for (int ks = 0; ks < 4; ++ks){
    int c0 = ks*8 + grp*2;
    float4 xa = xs4[xrow*32 + ((c0     + xrow*2) & 31)];
    float4 xb = xs4[xrow*32 + ((c0 + 1 + xrow*2) & 31)];
    bfrag8 af;
    af[0] = (short)f2bf(xa.x*wgt + bia);
    af[1] = (short)f2bf(xa.y*wgt + bia);
    af[2] = (short)f2bf(xa.z*wgt + bia);
    af[3] = (short)f2bf(xa.w*wgt + bia);
    af[4] = (short)f2bf(xb.x*wgt + bia);
    af[5] = (short)f2bf(xb.y*wgt + bia);
    af[6] = (short)f2bf(xb.z*wgt + bia);
    af[7] = (short)f2bf(xb.w*wgt + bia);
    #pragma unroll
    for (int nf = 0; nf < 4; ++nf){
      int dp = ch*64 + nf*16 + l15;
      bfrag8 bf = *reinterpret_cast<const bfrag8*>(
          lds + dp*128 + ((((ks*4 + grp)*8)) ^ ((dp&15)<<3)));
      acc[nf] = __builtin_amdgcn_mfma_f32_16x16x32_bf16(af, bf, acc[nf], 0, 0, 0);
    }
  }

  #pragma unroll
  for (int r = 0; r < 4; ++r){
    float s = 0.f, qq = 0.f;
    #pragma unroll
    for (int nf = 0; nf < 4; ++nf){ float v = acc[nf][r]; s += v; qq += v*v; }
    #pragma unroll
    for (int m = 1; m < 16; m <<= 1){ s += __shfl_xor(s, m); qq += __shfl_xor(qq, m); }
    if (l15 == 0) lnx[ch*64 + rh*16 + grp*4 + r] = make_float2(s, qq);
  }
  __syncthreads();

  float gc[4], bc[4];
  #pragma unroll
  for (int nf = 0; nf < 4; ++nf){
    int col = ch*64 + nf*16 + l15;
    gc[nf] = gamma[col]; bc[nf] = beta[col];
  }

  #pragma unroll
  for (int r = 0; r < 4; ++r){
    const int lrow = rh*16 + grp*4 + r;
    float2 pa = lnx[lrow], pb = lnx[64 + lrow];
    float s = pa.x + pb.x, qq = pa.y + pb.y;
    float mu = s * 0.0078125f;
    float var = fmaxf(qq*0.0078125f - mu*mu, 0.f);
    float rstd = rsqrtf(var + 1e-5f);
    const int rC = blockIdx.x*64 + lrow;
    #pragma unroll
    for (int nf = 0; nf < 4; ++nf){
      float hn = (acc[nf][r] - mu)*rstd*gc[nf] + bc[nf];
      acc[nf][r] = hn;
      h_lnB[(size_t)rC*DD + ch*64 + nf*16 + l15] = f2bf(hn);
    }
  }

  __syncthreads();   // reuse smem as hb[64 n][128 d] bf16
  #pragma unroll
  for (int r = 0; r < 4; ++r)
    #pragma unroll
    for (int nf = 0; nf < 4; ++nf)
      lds[(rh*16 + grp*4 + r)*128 + ch*64 + nf*16 + l15] = f2bf(acc[nf][r]);
  __syncthreads();

  {
    const int r0 = blockIdx.x*64;
    const int bB = r0 >> 12;
    const int nt = (r0 & 4095) >> 6;
    char* dstt = hTi8 + (((size_t)(bB*64 + nt)*128) << 6);
    const int d = tid & 127, q4 = tid >> 7;
    int pk[4];
    #pragma unroll
    for (int j = 0; j < 4; ++j){
      U32 word = 0;
      #pragma unroll
      for (int c = 0; c < 4; ++c){
        float v = bf2f((U32)lds[(q4*16 + j*4 + c)*128 + d]);
        float qf = fminf(fmaxf(rintf(v*32.f), -127.f), 127.f);
        int qi = (int)qf;
        word |= ((U32)(qi & 0xFF)) << (c*8);
      }
      pk[j] = (int)word;
    }
    int4 pa; pa.x = pk[0]; pa.y = pk[1]; pa.z = pk[2]; pa.w = pk[3];
    *reinterpret_cast<int4*>(dstt + (size_t)d*64 + q4*16) = pa;
  }
}

// ---------------- kernel 2: S = mask@h via i8 MFMA (FROZEN R15, 43.3µs config) ----
__global__ __launch_bounds__(512, 2) void k2_main(
    const U32* __restrict__ adjbT, const char* __restrict__ hTi8,
    const U16* __restrict__ h_lnB, float* __restrict__ out)
{
  __shared__ int part[32768];                // 128 KB: 4 regions x [64 r][128 c] i32
  const int tid = threadIdx.x;
  const int lane = tid & 63, w = tid >> 6;   // w = K-eighth
  const int l15 = lane & 15, grp = lane >> 4;
  const int bid = blockIdx.x;
  const int xcd = bid & 7;
  const int b = xcd >> 1;                    // batch pinned to XCD pair
  const int iblk = (((bid >> 3) << 1) | (xcd & 1)) * 64;
  const float CM2 = 0.2f * -9.0e15f / 32.0f; // leaky(MASK_VAL) / quant scale
  const U32 MUL = 0x00204081u;

  const U32* ar0 = adjbT + (size_t)(w*16)*4096 + iblk +      l15;
  const U32* ar1 = adjbT + (size_t)(w*16)*4096 + iblk + 16 + l15;
  const U32* ar2 = adjbT + (size_t)(w*16)*4096 + iblk + 32 + l15;
  const U32* ar3 = adjbT + (size_t)(w*16)*4096 + iblk + 48 + l15;

  const char* bp = hTi8 + (((size_t)(b*64 + w*8)*128) << 6) + l15*64 + grp*16;

  i32x4 acc[4][8] = {};

#define LOADB(P0,P1,P2,P3,P4,P5,P6,P7, S) do { \
    const char* _q = bp + (size_t)(S)*8192; \
    P0 = *reinterpret_cast<const i32x4*>(_q);        \
    P1 = *reinterpret_cast<const i32x4*>(_q + 1024); \
    P2 = *reinterpret_cast<const i32x4*>(_q + 2048); \
    P3 = *reinterpret_cast<const i32x4*>(_q + 3072); \
    P4 = *reinterpret_cast<const i32x4*>(_q + 4096); \
    P5 = *reinterpret_cast<const i32x4*>(_q + 5120); \
    P6 = *reinterpret_cast<const i32x4*>(_q + 6144); \
    P7 = *reinterpret_cast<const i32x4*>(_q + 7168); } while(0)

#define LOADW(L0,H0,L1,H1,L2,H2,L3,H3, S) do { \
    L0 = ar0[(size_t)(2*(S))*4096];   H0 = ar0[(size_t)(2*(S)+1)*4096]; \
    L1 = ar1[(size_t)(2*(S))*4096];   H1 = ar1[(size_t)(2*(S)+1)*4096]; \
    L2 = ar2[(size_t)(2*(S))*4096];   H2 = ar2[(size_t)(2*(S)+1)*4096]; \
    L3 = ar3[(size_t)(2*(S))*4096];   H3 = ar3[(size_t)(2*(S)+1)*4096]; } while(0)

#define COLM(CF, NF) do { \
    acc[0][NF] = __builtin_amdgcn_mfma_i32_16x16x64_i8(a0, CF, acc[0][NF], 0,0,0); \
    acc[1][NF] = __builtin_amdgcn_mfma_i32_16x16x64_i8(a1, CF, acc[1][NF], 0,0,0); \
    acc[2][NF] = __builtin_amdgcn_mfma_i32_16x16x64_i8(a2, CF, acc[2][NF], 0,0,0); \
    acc[3][NF] = __builtin_amdgcn_mfma_i32_16x16x64_i8(a3, CF, acc[3][NF], 0,0,0); } while(0)

#define COMPUTE(P0,P1,P2,P3,P4,P5,P6,P7, L0,H0,L1,H1,L2,H2,L3,H3) do { \
    i32x4 a0 = afragi8(L0, H0, grp, MUL); \
    i32x4 a1 = afragi8(L1, H1, grp, MUL); \
    i32x4 a2 = afragi8(L2, H2, grp, MUL); \
    i32x4 a3 = afragi8(L3, H3, grp, MUL); \
    COLM(P0, 0); COLM(P1, 1); COLM(P2, 2); COLM(P3, 3); \
    COLM(P4, 4); COLM(P5, 5); COLM(P6, 6); COLM(P7, 7); } while(0)

  i32x4 A0,A1,A2,A3,A4,A5,A6,A7, B0,B1,B2,B3,B4,B5,B6,B7;
  U32 aL0,aH0,aL1,aH1,aL2,aH2,aL3,aH3;
  U32 bL0,bH0,bL1,bH1,bL2,bH2,bL3,bH3;

  LOADB(A0,A1,A2,A3,A4,A5,A6,A7, 0);
  LOADW(aL0,aH0,aL1,aH1,aL2,aH2,aL3,aH3, 0);

  #pragma unroll 1
  for (int it = 0; it < 4; ++it){
    const int s = it*2;
    LOADB(B0,B1,B2,B3,B4,B5,B6,B7, s+1);
    LOADW(bL0,bH0,bL1,bH1,bL2,bH2,bL3,bH3, s+1);
    COMPUTE(A0,A1,A2,A3,A4,A5,A6,A7, aL0,aH0,aL1,aH1,aL2,aH2,aL3,aH3);
    LOADB(A0,A1,A2,A3,A4,A5,A6,A7, s+2);     // s+2==8 on last iter: reads pad
    LOADW(aL0,aH0,aL1,aH1,aL2,aH2,aL3,aH3, s+2);
    COMPUTE(B0,B1,B2,B3,B4,B5,B6,B7, bL0,bH0,bL1,bH1,bL2,bH2,bL3,bH3);
  }

  // ---- exact i32 K-combine: 4 regions; waves 0-3 write, 4-7 RMW-add ----
  {
    int* reg = part + (w & 3)*8192;
    if (w < 4){
      #pragma unroll
      for (int f = 0; f < 4; ++f)
        #pragma unroll
        for (int nf = 0; nf < 8; ++nf){
          const int col = nf*16 + l15;
          #pragma unroll
          for (int r = 0; r < 4; ++r){
            const int lr = f*16 + grp*4 + r;
            reg[lr*128 + (col ^ (((lr>>2)&3)<<4))] = acc[f][nf][r];
          }
        }
    }
    __syncthreads();
    if (w >= 4){
      #pragma unroll
      for (int f = 0; f < 4; ++f)
        #pragma unroll
        for (int nf = 0; nf < 8; ++nf){
          const int col = nf*16 + l15;
          #pragma unroll
          for (int r = 0; r < 4; ++r){
            const int lr = f*16 + grp*4 + r;
            const int idx = lr*128 + (col ^ (((lr>>2)&3)<<4));
            reg[idx] += acc[f][nf][r];
          }
        }
    }
    __syncthreads();
  }

  // ---- epilogue: 8 rows/wave, sum 4 regions, elu + residual ----
  #pragma unroll
  for (int rr = 0; rr < 8; ++rr){
    const int row = w*8 + rr;
    const int sw = ((row>>2)&3)<<4;
    const int idx = row*128 + ((2*lane) ^ sw);  // pair-safe: sw has no bit0
    int s0 = 0, s1 = 0;
    #pragma unroll
    for (int q = 0; q < 4; ++q){
      int2 v = *reinterpret_cast<const int2*>(part + q*8192 + idx);
      s0 += v.x; s1 += v.y;
    }
    const float h0 = CM2 * (float)s0, h1 = CM2 * (float)s1;
    const float e0 = h0 > 0.f ? h0 : __expf(h0) - 1.f;
    const float e1 = h1 > 0.f ? h1 : __expf(h1) - 1.f;
    const size_t o = ((size_t)b*NN + iblk + row)*DD + 2*lane;
    const U32 hl = *reinterpret_cast<const U32*>(h_lnB + o);
    float2 ov; ov.x = e0 + bf2f(hl & 0xffffu); ov.y = e1 + bf2f(hl >> 16);
    *reinterpret_cast<float2*>(out + o) = ov;
  }
#undef COLM
#undef COMPUTE
#undef LOADW
#undef LOADB
}

extern "C" void kernel_launch(void* const* d_in, const int* in_sizes, int n_in,
                              void* d_out, int out_size, void* d_ws, size_t ws_size,
                              hipStream_t stream) {
  const float* x     = (const float*)d_in[0];
  const int*   adj   = (const int*)  d_in[1];
  const float* W     = (const float*)d_in[2];
  const float* nw    = (const float*)d_in[5];
  const float* nb    = (const float*)d_in[6];
  const float* gamma = (const float*)d_in[7];
  const float* beta  = (const float*)d_in[8];
  float* out = (float*)d_out;

  char* ws = (char*)d_ws;
  U16*  h_lnB = (U16*)(ws);                             // 4 MB
  char* hTi8  = (char*)(ws + 4*1024*1024);              // 2 MB + pad
  U16*  WT    = (U16*)(ws + 6*1024*1024 + 64*1024);     // 32 KB
  U32*  adjbT = (U32*)(ws + 7*1024*1024);               // 2 MB (+overrun pad)

  k0_wt<<<dim3(64),   dim3(256), 0, stream>>>(W, WT);
  kP   <<<dim3(1280), dim3(512), 0, stream>>>(x, WT, adj, nw, nb, gamma, beta,
                                              h_lnB, hTi8, adjbT);
  k2_main<<<dim3(256), dim3(512), 0, stream>>>(adjbT, hTi8, h_lnB, out);
}

// Round 19
// 43.157 us; speedup vs baseline: 1.0038x; 1.0038x over previous
//
#include <hip/hip_runtime.h>
#include <hip/hip_bf16.h>

typedef short bfrag8 __attribute__((ext_vector_type(8)));
typedef float f32x4v __attribute__((ext_vector_type(4)));
typedef int i32x4 __attribute__((ext_vector_type(4)));
typedef unsigned short U16;
typedef unsigned int U32;

#define NN 4096
#define DD 128

static __device__ __forceinline__ U16 f2bf(float f){
  union { __hip_bfloat16 b; U16 u; } cv;
  cv.b = __float2bfloat16(f);
  return cv.u;
}

static __device__ __forceinline__ float bf2f(U32 u){
  union { float f; U32 u; } cv;
  cv.u = u << 16;
  return cv.f;
}

// i8 A-fragment (4 regs, 16 bytes of 0/1) from INVERTED adjacency bits.
static __device__ __forceinline__ i32x4 afragi8(U32 wl, U32 wh, int grp, U32 mul){
  U32 y = ((grp & 2) ? wh : wl) >> ((grp & 1) * 16);
  i32x4 a;
  a[0] = (int)((((y >>  0) & 0xFu) * mul) & 0x01010101u);
  a[1] = (int)((((y >>  4) & 0xFu) * mul) & 0x01010101u);
  a[2] = (int)((((y >>  8) & 0xFu) * mul) & 0x01010101u);
  a[3] = (int)((((y >> 12) & 0xFu) * mul) & 0x01010101u);
  return a;
}

// ---------------- kernel 0: adj pack TRANSPOSED+INVERTED (0..2047) + W^T ----------
__global__ __launch_bounds__(256) void k0_combo(const int* __restrict__ adj,
                                                U32* __restrict__ adjbT,
                                                const float* __restrict__ W,
                                                U16* __restrict__ WT){
  if (blockIdx.x >= 2048){
    int i = (blockIdx.x - 2048)*256 + threadIdx.x;  // i = d*128 + dp
    int d = i >> 7, dp = i & 127;
    WT[dp*128 + d] = f2bf(W[i]);
    return;
  }
  const int g   = blockIdx.x >> 4;                  // 0..127
  const int row = (blockIdx.x & 15)*256 + threadIdx.x;
  const int4* src = reinterpret_cast<const int4*>(adj + (size_t)row*NN + g*32);
  int4 v[8];
  #pragma unroll
  for (int c = 0; c < 8; ++c) v[c] = src[c];
  U32 m = 0;
  #pragma unroll
  for (int c = 0; c < 8; ++c){
    m |= (v[c].x != 0 ? 0u : 1u) << (c*4);
    m |= (v[c].y != 0 ? 0u : 2u) << (c*4);
    m |= (v[c].z != 0 ? 0u : 4u) << (c*4);
    m |= (v[c].w != 0 ? 0u : 8u) << (c*4);
  }
  adjbT[(size_t)g*4096 + row] = m;
}

// ---------------- kernel 1: 512 thr / 8 waves = 4 row-groups x 2 col-halves ------
// (frozen from R16) x2 = x*(nw+1)+nb; h = LN(x2@W); writes h_lnB + hTi8.
__global__ __launch_bounds__(512) void k1_prep(
    const float* __restrict__ x, const U16* __restrict__ WT,
    const float* __restrict__ nw, const float* __restrict__ nb,
    const float* __restrict__ gamma, const float* __restrict__ beta,
    U16* __restrict__ h_lnB, char* __restrict__ hTi8)
{
  __shared__ char smem[66560];               // 32K WT | 32K x-slab | 1K LN exchange
  U16* lds = reinterpret_cast<U16*>(smem);
  float4* xs4 = reinterpret_cast<float4*>(smem + 32768);
  float2* lnx = reinterpret_cast<float2*>(smem + 65536);   // [2 ch][64 rows]
  const int tid = threadIdx.x;
  const int lane = tid & 63, w = tid >> 6;
  const int rh = w >> 1, ch = w & 1;         // row-group (16 rows), col-half (64)
  const int l15 = lane & 15, grp = lane >> 4;

  #pragma unroll
  for (int q = 0; q < 4; ++q){
    int cid = q*512 + tid;
    int dp = cid >> 4, c = cid & 15;
    *reinterpret_cast<int4*>(lds + dp*128 + ((c*8) ^ ((dp&15)<<3))) =
        *reinterpret_cast<const int4*>(WT + cid*8);
  }
  {
    const float4* xg = reinterpret_cast<const float4*>(x) + (size_t)blockIdx.x*2048;
    #pragma unroll
    for (int k = 0; k < 4; ++k){
      int g = k*512 + tid;                   // 0..2047
      int row = g >> 5, c = g & 31;
      xs4[row*32 + ((c + row*2) & 31)] = xg[g];
    }
  }
  __syncthreads();

  const int rA = blockIdx.x*64 + rh*16 + l15;
  const int nA = rA & 4095;
  const float wgt = nw[nA] + 1.0f, bia = nb[nA];
  const int xrow = rh*16 + l15;              // row within slab

  f32x4v acc[4] = {};
  #pragma unroll
  for (int ks = 0; ks < 4; ++ks){
    int c0 = ks*8 + grp*2;
    float4 xa = xs4[xrow*32 + ((c0     + xrow*2) & 31)];
    float4 xb = xs4[xrow*32 + ((c0 + 1 + xrow*2) & 31)];
    bfrag8 af;
    af[0] = (short)f2bf(xa.x*wgt + bia);
    af[1] = (short)f2bf(xa.y*wgt + bia);
    af[2] = (short)f2bf(xa.z*wgt + bia);
    af[3] = (short)f2bf(xa.w*wgt + bia);
    af[4] = (short)f2bf(xb.x*wgt + bia);
    af[5] = (short)f2bf(xb.y*wgt + bia);
    af[6] = (short)f2bf(xb.z*wgt + bia);
    af[7] = (short)f2bf(xb.w*wgt + bia);
    #pragma unroll
    for (int nf = 0; nf < 4; ++nf){
      int dp = ch*64 + nf*16 + l15;
      bfrag8 bf = *reinterpret_cast<const bfrag8*>(
          lds + dp*128 + ((((ks*4 + grp)*8)) ^ ((dp&15)<<3)));
      acc[nf] = __builtin_amdgcn_mfma_f32_16x16x32_bf16(af, bf, acc[nf], 0, 0, 0);
    }
  }

  #pragma unroll
  for (int r = 0; r < 4; ++r){
    float s = 0.f, qq = 0.f;
    #pragma unroll
    for (int nf = 0; nf < 4; ++nf){ float v = acc[nf][r]; s += v; qq += v*v; }
    #pragma unroll
    for (int m = 1; m < 16; m <<= 1){ s += __shfl_xor(s, m); qq += __shfl_xor(qq, m); }
    if (l15 == 0) lnx[ch*64 + rh*16 + grp*4 + r] = make_float2(s, qq);
  }
  __syncthreads();

  float gc[4], bc[4];
  #pragma unroll
  for (int nf = 0; nf < 4; ++nf){
    int col = ch*64 + nf*16 + l15;
    gc[nf] = gamma[col]; bc[nf] = beta[col];
  }

  #pragma unroll
  for (int r = 0; r < 4; ++r){
    const int lrow = rh*16 + grp*4 + r;
    float2 pa = lnx[lrow], pb = lnx[64 + lrow];
    float s = pa.x + pb.x, qq = pa.y + pb.y;
    float mu = s * 0.0078125f;
    float var = fmaxf(qq*0.0078125f - mu*mu, 0.f);
    float rstd = rsqrtf(var + 1e-5f);
    const int rC = blockIdx.x*64 + lrow;
    #pragma unroll
    for (int nf = 0; nf < 4; ++nf){
      float hn = (acc[nf][r] - mu)*rstd*gc[nf] + bc[nf];
      acc[nf][r] = hn;
      h_lnB[(size_t)rC*DD + ch*64 + nf*16 + l15] = f2bf(hn);
    }
  }

  __syncthreads();   // reuse smem as hb[64 n][128 d] bf16
  #pragma unroll
  for (int r = 0; r < 4; ++r)
    #pragma unroll
    for (int nf = 0; nf < 4; ++nf)
      lds[(rh*16 + grp*4 + r)*128 + ch*64 + nf*16 + l15] = f2bf(acc[nf][r]);
  __syncthreads();

  {
    const int r0 = blockIdx.x*64;
    const int bB = r0 >> 12;
    const int nt = (r0 & 4095) >> 6;
    char* dstt = hTi8 + (((size_t)(bB*64 + nt)*128) << 6);
    const int d = tid & 127, q4 = tid >> 7;
    int pk[4];
    #pragma unroll
    for (int j = 0; j < 4; ++j){
      U32 word = 0;
      #pragma unroll
      for (int c = 0; c < 4; ++c){
        float v = bf2f((U32)lds[(q4*16 + j*4 + c)*128 + d]);
        float qf = fminf(fmaxf(rintf(v*32.f), -127.f), 127.f);
        int qi = (int)qf;
        word |= ((U32)(qi & 0xFF)) << (c*8);
      }
      pk[j] = (int)word;
    }
    int4 pa; pa.x = pk[0]; pa.y = pk[1]; pa.z = pk[2]; pa.w = pk[3];
    *reinterpret_cast<int4*>(dstt + (size_t)d*64 + q4*16) = pa;
  }
}

// ---------------- kernel 2: S = mask@h via i8 MFMA — naive FULL-UNROLL loop ------
// Same structure as R15 (8 waves = K-eighths, direct-to-reg B, XCD-pinned) but
// the main loop is a plain fully-unrolled per-step body: compile-time offsets,
// no manual banks -> compiler free to software-pipeline to its chosen depth.
__global__ __launch_bounds__(512, 2) void k2_main(
    const U32* __restrict__ adjbT, const char* __restrict__ hTi8,
    const U16* __restrict__ h_lnB, float* __restrict__ out)
{
  __shared__ int part[32768];                // 128 KB: 4 regions x [64 r][128 c] i32
  const int tid = threadIdx.x;
  const int lane = tid & 63, w = tid >> 6;   // w = K-eighth
  const int l15 = lane & 15, grp = lane >> 4;
  const int bid = blockIdx.x;
  const int xcd = bid & 7;
  const int b = xcd >> 1;                    // batch pinned to XCD pair
  const int iblk = (((bid >> 3) << 1) | (xcd & 1)) * 64;
  const float CM2 = 0.2f * -9.0e15f / 32.0f; // leaky(MASK_VAL) / quant scale
  const U32 MUL = 0x00204081u;

  const U32* ar0 = adjbT + (size_t)(w*16)*4096 + iblk +      l15;
  const U32* ar1 = adjbT + (size_t)(w*16)*4096 + iblk + 16 + l15;
  const U32* ar2 = adjbT + (size_t)(w*16)*4096 + iblk + 32 + l15;
  const U32* ar3 = adjbT + (size_t)(w*16)*4096 + iblk + 48 + l15;

  const char* bp = hTi8 + (((size_t)(b*64 + w*8)*128) << 6) + l15*64 + grp*16;

  i32x4 acc[4][8] = {};

  #pragma unroll
  for (int s = 0; s < 8; ++s){               // full unroll: compiler pipelines
    const char* _q = bp + (size_t)s*8192;
    i32x4 F0 = *reinterpret_cast<const i32x4*>(_q);
    i32x4 F1 = *reinterpret_cast<const i32x4*>(_q + 1024);
    i32x4 F2 = *reinterpret_cast<const i32x4*>(_q + 2048);
    i32x4 F3 = *reinterpret_cast<const i32x4*>(_q + 3072);
    i32x4 F4 = *reinterpret_cast<const i32x4*>(_q + 4096);
    i32x4 F5 = *reinterpret_cast<const i32x4*>(_q + 5120);
    i32x4 F6 = *reinterpret_cast<const i32x4*>(_q + 6144);
    i32x4 F7 = *reinterpret_cast<const i32x4*>(_q + 7168);
    const U32 L0 = ar0[(size_t)(2*s)*4096], H0 = ar0[(size_t)(2*s+1)*4096];
    const U32 L1 = ar1[(size_t)(2*s)*4096], H1 = ar1[(size_t)(2*s+1)*4096];
    const U32 L2 = ar2[(size_t)(2*s)*4096], H2 = ar2[(size_t)(2*s+1)*4096];
    const U32 L3 = ar3[(size_t)(2*s)*4096], H3 = ar3[(size_t)(2*s+1)*4096];
    i32x4 a0 = afragi8(L0, H0, grp, MUL);
    i32x4 a1 = afragi8(L1, H1, grp, MUL);
    i32x4 a2 = afragi8(L2, H2, grp, MUL);
    i32x4 a3 = afragi8(L3, H3, grp, MUL);
#define COLM(CF, NF) \
    acc[0][NF] = __builtin_amdgcn_mfma_i32_16x16x64_i8(a0, CF, acc[0][NF], 0,0,0); \
    acc[1][NF] = __builtin_amdgcn_mfma_i32_16x16x64_i8(a1, CF, acc[1][NF], 0,0,0); \
    acc[2][NF] = __builtin_amdgcn_mfma_i32_16x16x64_i8(a2, CF, acc[2][NF], 0,0,0); \
    acc[3][NF] = __builtin_amdgcn_mfma_i32_16x16x64_i8(a3, CF, acc[3][NF], 0,0,0);
    COLM(F0, 0); COLM(F1, 1); COLM(F2, 2); COLM(F3, 3);
    COLM(F4, 4); COLM(F5, 5); COLM(F6, 6); COLM(F7, 7);
#undef COLM
  }

  // ---- exact i32 K-combine: 4 regions; waves 0-3 write, 4-7 RMW-add ----
  {
    int* reg = part + (w & 3)*8192;
    if (w < 4){
      #pragma unroll
      for (int f = 0; f < 4; ++f)
        #pragma unroll
        for (int nf = 0; nf < 8; ++nf){
          const int col = nf*16 + l15;
          #pragma unroll
          for (int r = 0; r < 4; ++r){
            const int lr = f*16 + grp*4 + r;
            reg[lr*128 + (col ^ (((lr>>2)&3)<<4))] = acc[f][nf][r];
          }
        }
    }
    __syncthreads();
    if (w >= 4){
      #pragma unroll
      for (int f = 0; f < 4; ++f)
        #pragma unroll
        for (int nf = 0; nf < 8; ++nf){
          const int col = nf*16 + l15;
          #pragma unroll
          for (int r = 0; r < 4; ++r){
            const int lr = f*16 + grp*4 + r;
            const int idx = lr*128 + (col ^ (((lr>>2)&3)<<4));
            reg[idx] += acc[f][nf][r];
          }
        }
    }
    __syncthreads();
  }

  // ---- epilogue: 8 rows/wave, sum 4 regions, elu + residual ----
  #pragma unroll
  for (int rr = 0; rr < 8; ++rr){
    const int row = w*8 + rr;
    const int sw = ((row>>2)&3)<<4;
    const int idx = row*128 + ((2*lane) ^ sw);  // pair-safe: sw has no bit0
    int s0 = 0, s1 = 0;
    #pragma unroll
    for (int q = 0; q < 4; ++q){
      int2 v = *reinterpret_cast<const int2*>(part + q*8192 + idx);
      s0 += v.x; s1 += v.y;
    }
    const float h0 = CM2 * (float)s0, h1 = CM2 * (float)s1;
    const float e0 = h0 > 0.f ? h0 : __expf(h0) - 1.f;
    const float e1 = h1 > 0.f ? h1 : __expf(h1) - 1.f;
    const size_t o = ((size_t)b*NN + iblk + row)*DD + 2*lane;
    const U32 hl = *reinterpret_cast<const U32*>(h_lnB + o);
    float2 ov; ov.x = e0 + bf2f(hl & 0xffffu); ov.y = e1 + bf2f(hl >> 16);
    *reinterpret_cast<float2*>(out + o) = ov;
  }
}

extern "C" void kernel_launch(void* const* d_in, const int* in_sizes, int n_in,
                              void* d_out, int out_size, void* d_ws, size_t ws_size,
                              hipStream_t stream) {
  const float* x     = (const float*)d_in[0];
  const int*   adj   = (const int*)  d_in[1];
  const float* W     = (const float*)d_in[2];
  const float* nw    = (const float*)d_in[5];
  const float* nb    = (const float*)d_in[6];
  const float* gamma = (const float*)d_in[7];
  const float* beta  = (const float*)d_in[8];
  float* out = (float*)d_out;

  char* ws = (char*)d_ws;
  U16*  h_lnB = (U16*)(ws);                             // 4 MB
  char* hTi8  = (char*)(ws + 4*1024*1024);              // 2 MB + pad
  U16*  WT    = (U16*)(ws + 6*1024*1024 + 64*1024);     // 32 KB
  U32*  adjbT = (U32*)(ws + 7*1024*1024);               // 2 MB

  k0_combo<<<dim3(2112), dim3(256), 0, stream>>>(adj, adjbT, W, WT);
  k1_prep <<<dim3(256),  dim3(512), 0, stream>>>(x, WT, nw, nb, gamma, beta,
                                                 h_lnB, hTi8);
  k2_main <<<dim3(256),  dim3(512), 0, stream>>>(adjbT, hTi8, h_lnB, out);
}